// Round 7
// baseline (323.729 us; speedup 1.0000x reference)
//
#include <hip/hip_runtime.h>

#define N_NODES 50000
#define N_EDGES 800000
#define HID 128
#define OUT_CH 64
#define LDA 264         // LDS A-tile row stride in bf16 elems (256 + 8 pad)
#define NSLAB 8
#define SLAB_DIV 6250   // nodes per slab (50000/8)
#define NKEY (N_NODES * NSLAB)          // 400000
#define SCAN2_BLOCKS ((NKEY + 255) / 256)  // 1563

typedef __attribute__((ext_vector_type(8))) short bf16x8;
typedef __attribute__((ext_vector_type(4))) float f32x4;

__device__ __forceinline__ float bf2f(unsigned int bits16) {
    return __uint_as_float(bits16 << 16);
}
__device__ __forceinline__ unsigned short f2bf(float f) {
    unsigned int u = __float_as_uint(f);
    u = (u + 0x7fffu + ((u >> 16) & 1u)) >> 16;
    return (unsigned short)u;
}
__device__ __forceinline__ void acc_u4(float* a, uint4 v) {
    a[0] += bf2f(v.x & 0xffffu); a[1] += bf2f(v.x >> 16);
    a[2] += bf2f(v.y & 0xffffu); a[3] += bf2f(v.y >> 16);
    a[4] += bf2f(v.z & 0xffffu); a[5] += bf2f(v.z >> 16);
    a[6] += bf2f(v.w & 0xffffu); a[7] += bf2f(v.w >> 16);
}
__device__ __forceinline__ int slabOf(int s) { return s / SLAB_DIV; }

// ---------------- slab-phased gather: wave fills 4 rows of sA mean-agg ----------------
// Edge lists are grouped by src-slab within each dst row (row_ptr2 keyed dst*8+slab).
// Outer loop over slabs -> all resident blocks touch the same 1.6 MB slab window
// at roughly the same time -> src rows become L2-resident.
// Lane = g*16 + c: group g covers edge slot b*4+g, chunk c covers channels 8c..8c+7.
__device__ __forceinline__ void gather8(
    const unsigned short* __restrict__ feat,
    const int* __restrict__ row_ptr2, const int* __restrict__ esrc,
    int m0, unsigned short* __restrict__ sA)
{
    const int tid = threadIdx.x;
    const int wave = tid >> 6, lane = tid & 63;
    const int g = lane >> 4, c = lane & 15;
    const int base = m0 + wave * 4;

    // 33 consecutive boundaries: row_ptr2[base*8 + 0..32]
    const int bl = (lane <= 32) ? lane : 32;
    const int bv = row_ptr2[base * NSLAB + bl];

    float acc[4][8];
    #pragma unroll
    for (int j = 0; j < 4; ++j)
        #pragma unroll
        for (int k = 0; k < 8; ++k) acc[j][k] = 0.0f;

    for (int s = 0; s < NSLAB; ++s) {
        #pragma unroll
        for (int j = 0; j < 4; ++j) {
            const int beg = __shfl(bv, j * 8 + s);
            const int deg = __shfl(bv, j * 8 + s + 1) - beg;
            if (deg <= 0) continue;                      // wave-uniform
            for (int e0 = 0; e0 < deg; e0 += 16) {
                int ei = e0 + c;
                int id = esrc[beg + ((ei < deg) ? ei : (deg - 1))];
                #pragma unroll
                for (int b = 0; b < 4; ++b) {
                    if (e0 + b * 4 >= deg) break;        // wave-uniform
                    int sid = __shfl(id, b * 4 + g);
                    uint4 v = make_uint4(0u, 0u, 0u, 0u);
                    if (e0 + b * 4 + g < deg)            // exec-masked load
                        v = *reinterpret_cast<const uint4*>(feat + (size_t)sid * HID + c * 8);
                    acc_u4(acc[j], v);
                }
            }
        }
    }

    #pragma unroll
    for (int j = 0; j < 4; ++j) {
        const int degT = __shfl(bv, j * 8 + 8) - __shfl(bv, j * 8);
        const float scale = 1.0f / fmaxf((float)degT, 1.0f);
        float r[8];
        #pragma unroll
        for (int k = 0; k < 8; ++k) {
            float t = acc[j][k];
            t += __shfl_xor(t, 16);
            t += __shfl_xor(t, 32);
            r[k] = t * scale;
        }
        if (g == 0) {
            uint4 pk;
            pk.x = (unsigned)f2bf(r[0]) | ((unsigned)f2bf(r[1]) << 16);
            pk.y = (unsigned)f2bf(r[2]) | ((unsigned)f2bf(r[3]) << 16);
            pk.z = (unsigned)f2bf(r[4]) | ((unsigned)f2bf(r[5]) << 16);
            pk.w = (unsigned)f2bf(r[6]) | ((unsigned)f2bf(r[7]) << 16);
            *reinterpret_cast<uint4*>(&sA[(wave * 4 + j) * LDA + c * 8]) = pk;
        }
    }
}

// ---------------- convert x -> bf16 [N][128]; weights -> bf16 [128][256] ----------------
__global__ __launch_bounds__(256) void convert_kernel(
    const float* __restrict__ x, unsigned short* __restrict__ xb,
    const float* __restrict__ Wl1, const float* __restrict__ Wr1,
    const float* __restrict__ Wl2, const float* __restrict__ Wr2,
    unsigned short* __restrict__ wcat1, unsigned short* __restrict__ wcat2)
{
    const int b = blockIdx.x;
    if (b < N_NODES * 32 / 256) {
        int gid = b * 256 + threadIdx.x;          // over N*32
        int node = gid >> 5, c4 = gid & 31;
        float4 v = reinterpret_cast<const float4*>(x + (size_t)node * HID)[c4];
        unsigned short* o = xb + (size_t)node * HID + c4 * 4;
        o[0] = f2bf(v.x); o[1] = f2bf(v.y); o[2] = f2bf(v.z); o[3] = f2bf(v.w);
    } else {
        int idx2 = (b - N_NODES * 32 / 256) * 256 + threadIdx.x;  // over 2*128*256
        int layer = idx2 >> 15;
        int idx = idx2 & 32767;
        int n = idx >> 8, k = idx & 255;
        const float* Wl = layer ? Wl2 : Wl1;
        const float* Wr = layer ? Wr2 : Wr1;
        float v = (k < 128) ? Wl[(size_t)n * HID + k] : Wr[(size_t)n * HID + (k - 128)];
        (layer ? wcat2 : wcat1)[idx] = f2bf(v);
    }
}

// ---------------- (dst,slab) histogram ----------------
__global__ void hist2_kernel(const int* __restrict__ src, const int* __restrict__ dst,
                             int* __restrict__ cnt2) {
    int e = blockIdx.x * blockDim.x + threadIdx.x;
    if (e < N_EDGES)
        atomicAdd(&cnt2[dst[e] * NSLAB + slabOf(src[e])], 1);
}

// ---------------- 3-phase exclusive scan over NKEY counters ----------------
__global__ __launch_bounds__(256) void scanA_kernel(const int* __restrict__ cnt2,
                                                    int* __restrict__ partial) {
    const int tid = threadIdx.x;
    const int i = blockIdx.x * 256 + tid;
    int v = (i < NKEY) ? cnt2[i] : 0;
    const int lane = tid & 63, wave = tid >> 6;
    int incl = v;
    #pragma unroll
    for (int off = 1; off < 64; off <<= 1) {
        int t = __shfl_up(incl, off);
        if (lane >= off) incl += t;
    }
    __shared__ int wsum[4];
    if (lane == 63) wsum[wave] = incl;
    __syncthreads();
    if (tid == 0) partial[blockIdx.x] = wsum[0] + wsum[1] + wsum[2] + wsum[3];
}

__global__ __launch_bounds__(1024) void scanB_kernel(int* __restrict__ partial) {
    const int tid = threadIdx.x;
    const int M = SCAN2_BLOCKS;
    const int CHUNK = (M + 1023) / 1024;   // 2
    const int beg = tid * CHUNK;
    const int end = (beg + CHUNK < M) ? beg + CHUNK : M;
    int sum = 0;
    for (int i = beg; i < end; ++i) sum += partial[i];

    const int lane = tid & 63, wave = tid >> 6;
    int incl = sum;
    #pragma unroll
    for (int off = 1; off < 64; off <<= 1) {
        int t = __shfl_up(incl, off);
        if (lane >= off) incl += t;
    }
    __shared__ int wsum[16];
    if (lane == 63) wsum[wave] = incl;
    __syncthreads();
    if (wave == 0 && lane < 16) {
        int w = wsum[lane];
        #pragma unroll
        for (int off = 1; off < 16; off <<= 1) {
            int t = __shfl_up(w, off);
            if (lane >= off) w += t;
        }
        wsum[lane] = w;
    }
    __syncthreads();
    const int waveBase = (wave > 0) ? wsum[wave - 1] : 0;
    int run = waveBase + incl - sum;
    for (int i = beg; i < end; ++i) {
        int cc = partial[i];
        partial[i] = run;
        run += cc;
    }
}

__global__ __launch_bounds__(256) void scanC_kernel(int* __restrict__ cnt2,
                                                    const int* __restrict__ partial,
                                                    int* __restrict__ row_ptr2) {
    const int tid = threadIdx.x;
    const int i = blockIdx.x * 256 + tid;
    int v = (i < NKEY) ? cnt2[i] : 0;
    const int lane = tid & 63, wave = tid >> 6;
    int incl = v;
    #pragma unroll
    for (int off = 1; off < 64; off <<= 1) {
        int t = __shfl_up(incl, off);
        if (lane >= off) incl += t;
    }
    __shared__ int wsum[4];
    if (lane == 63) wsum[wave] = incl;
    __syncthreads();
    int base = partial[blockIdx.x];
    if (wave > 0) base += wsum[0];
    if (wave > 1) base += wsum[1];
    if (wave > 2) base += wsum[2];
    const int pre = base + incl - v;
    if (i < NKEY) {
        cnt2[i] = pre;                  // fill cursor
        row_ptr2[i + 1] = pre + v;
    }
    if (i == 0) row_ptr2[0] = 0;
}

// ---------------- bucket fill by (dst,slab) ----------------
__global__ void fill2_kernel(const int* __restrict__ src, const int* __restrict__ dst,
                             int* __restrict__ cursor, int* __restrict__ esrc) {
    int e = blockIdx.x * blockDim.x + threadIdx.x;
    if (e < N_EDGES) {
        int sv = src[e];
        int p = atomicAdd(&cursor[dst[e] * NSLAB + slabOf(sv)], 1);
        esrc[p] = sv;
    }
}

// ---------------- fused gather + SAGE layer-1 MFMA ----------------
__global__ __launch_bounds__(256) void sage1_kernel(
    const unsigned short* __restrict__ feat,
    const int* __restrict__ row_ptr2, const int* __restrict__ esrc,
    const unsigned short* __restrict__ Wcat, const float* __restrict__ bias,
    unsigned short* __restrict__ Hout)
{
    __shared__ unsigned short sA[16 * LDA];
    const int tid = threadIdx.x;
    const int wave = tid >> 6, lane = tid & 63;
    const int m0 = blockIdx.x * 16;

    // self columns: sA[r][128..255]
    {
        int r = tid >> 4, cc = tid & 15;
        uint4 v = reinterpret_cast<const uint4*>(feat + (size_t)(m0 + r) * HID)[cc];
        *reinterpret_cast<uint4*>(&sA[r * LDA + 128 + cc * 8]) = v;
    }
    gather8(feat, row_ptr2, esrc, m0, sA);
    __syncthreads();

    const int l15 = lane & 15, lq = lane >> 4;
    const int n0 = wave * 32;
    bf16x8 bfrag[2][8];
    #pragma unroll
    for (int nt = 0; nt < 2; ++nt) {
        const unsigned short* wrow = Wcat + (size_t)(n0 + nt * 16 + l15) * 256;
        #pragma unroll
        for (int ks = 0; ks < 8; ++ks)
            bfrag[nt][ks] = *reinterpret_cast<const bf16x8*>(wrow + ks * 32 + lq * 8);
    }
    f32x4 acc0 = {0.f, 0.f, 0.f, 0.f}, acc1 = {0.f, 0.f, 0.f, 0.f};
    #pragma unroll
    for (int ks = 0; ks < 8; ++ks) {
        bf16x8 af = *reinterpret_cast<const bf16x8*>(&sA[l15 * LDA + ks * 32 + lq * 8]);
        acc0 = __builtin_amdgcn_mfma_f32_16x16x32_bf16(af, bfrag[0][ks], acc0, 0, 0, 0);
        acc1 = __builtin_amdgcn_mfma_f32_16x16x32_bf16(af, bfrag[1][ks], acc1, 0, 0, 0);
    }
    #pragma unroll
    for (int nt = 0; nt < 2; ++nt) {
        const f32x4 a = nt ? acc1 : acc0;
        const int col = n0 + nt * 16 + l15;
        const float bv = bias[col];
        #pragma unroll
        for (int r = 0; r < 4; ++r) {
            float v = fmaxf(a[r] + bv, 0.0f);      // relu
            Hout[(size_t)(m0 + lq * 4 + r) * HID + col] = f2bf(v);
        }
    }
}

// ---------------- fused gather + layer-2 MFMA + head + log_softmax ----------------
__global__ __launch_bounds__(256) void final_kernel(
    const unsigned short* __restrict__ feat,    // h1 [N][128] bf16
    const int* __restrict__ row_ptr2, const int* __restrict__ esrc,
    const unsigned short* __restrict__ Wcat2, const float* __restrict__ bl2,
    const float* __restrict__ Wout, const float* __restrict__ bout,
    float* __restrict__ out)
{
    __shared__ __align__(16) char smem[16 * LDA * 2 + 16 * OUT_CH * 4];  // 8448 + 4096
    unsigned short* sA = (unsigned short*)smem;            // phase 1-2
    float (*sH)[132]   = (float(*)[132])smem;              // overlay, phase 3+
    float (*sL)[OUT_CH] = (float(*)[OUT_CH])(smem + 16 * LDA * 2);
    const int tid = threadIdx.x;
    const int wave = tid >> 6, lane = tid & 63;
    const int m0 = blockIdx.x * 16;

    {
        int r = tid >> 4, cc = tid & 15;
        uint4 v = reinterpret_cast<const uint4*>(feat + (size_t)(m0 + r) * HID)[cc];
        *reinterpret_cast<uint4*>(&sA[r * LDA + 128 + cc * 8]) = v;
    }
    gather8(feat, row_ptr2, esrc, m0, sA);
    __syncthreads();

    const int l15 = lane & 15, lq = lane >> 4;
    const int n0 = wave * 32;
    bf16x8 bfrag[2][8];
    #pragma unroll
    for (int nt = 0; nt < 2; ++nt) {
        const unsigned short* wrow = Wcat2 + (size_t)(n0 + nt * 16 + l15) * 256;
        #pragma unroll
        for (int ks = 0; ks < 8; ++ks)
            bfrag[nt][ks] = *reinterpret_cast<const bf16x8*>(wrow + ks * 32 + lq * 8);
    }
    f32x4 acc0 = {0.f, 0.f, 0.f, 0.f}, acc1 = {0.f, 0.f, 0.f, 0.f};
    #pragma unroll
    for (int ks = 0; ks < 8; ++ks) {
        bf16x8 af = *reinterpret_cast<const bf16x8*>(&sA[l15 * LDA + ks * 32 + lq * 8]);
        acc0 = __builtin_amdgcn_mfma_f32_16x16x32_bf16(af, bfrag[0][ks], acc0, 0, 0, 0);
        acc1 = __builtin_amdgcn_mfma_f32_16x16x32_bf16(af, bfrag[1][ks], acc1, 0, 0, 0);
    }
    __syncthreads();   // all waves done reading sA before sH overlay write

    #pragma unroll
    for (int nt = 0; nt < 2; ++nt) {
        const f32x4 a = nt ? acc1 : acc0;
        const int col = n0 + nt * 16 + l15;
        const float bv = bl2[col];
        #pragma unroll
        for (int r = 0; r < 4; ++r)
            sH[lq * 4 + r][col] = a[r] + bv;
    }
    __syncthreads();

    // head: logits = h2 @ Wout^T + bout
    {
        const int o = tid & 63;
        const int jb = (tid >> 6) * 4;
        float hacc[4] = {0, 0, 0, 0};
        for (int k4 = 0; k4 < 32; ++k4) {
            float4 w = reinterpret_cast<const float4*>(Wout + (size_t)o * HID)[k4];
            #pragma unroll
            for (int j = 0; j < 4; ++j) {
                float4 h = *reinterpret_cast<const float4*>(&sH[jb + j][k4 * 4]);
                hacc[j] += w.x * h.x + w.y * h.y + w.z * h.z + w.w * h.w;
            }
        }
        const float bv = bout[o];
        #pragma unroll
        for (int j = 0; j < 4; ++j)
            sL[jb + j][o] = hacc[j] + bv;
    }
    __syncthreads();

    // log_softmax: one wave per row
    for (int r = wave; r < 16; r += 4) {
        float v = sL[r][lane];
        float m = v;
        for (int off = 32; off; off >>= 1) m = fmaxf(m, __shfl_xor(m, off));
        float ex = expf(v - m);
        float s = ex;
        for (int off = 32; off; off >>= 1) s += __shfl_xor(s, off);
        out[(size_t)(m0 + r) * OUT_CH + lane] = v - m - logf(s);
    }
}

extern "C" void kernel_launch(void* const* d_in, const int* in_sizes, int n_in,
                              void* d_out, int out_size, void* d_ws, size_t ws_size,
                              hipStream_t stream) {
    const float* x    = (const float*)d_in[0];
    const int*   edge = (const int*)d_in[1];
    const int*   src  = edge;
    const int*   dst  = edge + N_EDGES;
    const float* Wl1  = (const float*)d_in[2];
    const float* bl1  = (const float*)d_in[3];
    const float* Wr1  = (const float*)d_in[4];
    const float* Wl2  = (const float*)d_in[5];
    const float* bl2  = (const float*)d_in[6];
    const float* Wr2  = (const float*)d_in[7];
    const float* Wout = (const float*)d_in[8];
    const float* bout = (const float*)d_in[9];
    float* out = (float*)d_out;

    char* ws = (char*)d_ws;
    const size_t featBytes = (size_t)N_NODES * HID * 2;          // 12.8 MB
    unsigned short* xb = (unsigned short*)ws;
    unsigned short* h1 = (unsigned short*)(ws + featBytes);
    char* p = ws + 2 * featBytes;
    int* cnt2     = (int*)p;   p += (size_t)NKEY * 4;
    int* row_ptr2 = (int*)p;   p += (size_t)(NKEY + 1) * 4 + 252;
    int* partial  = (int*)p;   p += (size_t)SCAN2_BLOCKS * 4 + 340;
    int* esrc     = (int*)p;   p += (size_t)N_EDGES * 4;
    unsigned short* wcat1 = (unsigned short*)p;  p += 128 * 256 * 2;
    unsigned short* wcat2 = (unsigned short*)p;

    hipMemsetAsync(cnt2, 0, (size_t)NKEY * sizeof(int), stream);
    hist2_kernel<<<N_EDGES / 256, 256, 0, stream>>>(src, dst, cnt2);
    convert_kernel<<<N_NODES * 32 / 256 + 256, 256, 0, stream>>>(
        x, xb, Wl1, Wr1, Wl2, Wr2, wcat1, wcat2);
    scanA_kernel<<<SCAN2_BLOCKS, 256, 0, stream>>>(cnt2, partial);
    scanB_kernel<<<1, 1024, 0, stream>>>(partial);
    scanC_kernel<<<SCAN2_BLOCKS, 256, 0, stream>>>(cnt2, partial, row_ptr2);
    fill2_kernel<<<N_EDGES / 256, 256, 0, stream>>>(src, dst, cnt2, esrc);

    sage1_kernel<<<N_NODES / 16, 256, 0, stream>>>(xb, row_ptr2, esrc, wcat1, bl1, h1);
    final_kernel<<<N_NODES / 16, 256, 0, stream>>>(h1, row_ptr2, esrc, wcat2, bl2,
                                                   Wout, bout, out);
}

// Round 8
// 250.514 us; speedup vs baseline: 1.2923x; 1.2923x over previous
//
#include <hip/hip_runtime.h>

#define N_NODES 50000
#define N_EDGES 800000
#define HID 128
#define OUT_CH 64
#define LDA 264   // LDS A-tile row stride in bf16 elems (256 + 8 pad)
#define SCAN_BLOCKS 196  // ceil(50000/256)

typedef __attribute__((ext_vector_type(8))) short bf16x8;
typedef __attribute__((ext_vector_type(4))) float f32x4;

__device__ __forceinline__ float bf2f(unsigned int bits16) {
    return __uint_as_float(bits16 << 16);
}
__device__ __forceinline__ unsigned short f2bf(float f) {
    unsigned int u = __float_as_uint(f);
    u = (u + 0x7fffu + ((u >> 16) & 1u)) >> 16;
    return (unsigned short)u;
}
__device__ __forceinline__ void acc_u4(float* a, uint4 v) {
    a[0] += bf2f(v.x & 0xffffu); a[1] += bf2f(v.x >> 16);
    a[2] += bf2f(v.y & 0xffffu); a[3] += bf2f(v.y >> 16);
    a[4] += bf2f(v.z & 0xffffu); a[5] += bf2f(v.z >> 16);
    a[6] += bf2f(v.w & 0xffffu); a[7] += bf2f(v.w >> 16);
}

// ---------------- fp8 e4m3fn encode (cold path, convert kernel only) ----------------
__device__ __forceinline__ unsigned int f2fp8(float f) {
    unsigned int u = __float_as_uint(f);
    unsigned int s = (u >> 24) & 0x80u;
    float xa = fabsf(f);
    if (xa >= 0.015625f) {
        unsigned int a = __float_as_uint(xa);
        if (a > 0x43E00000u) a = 0x43E00000u;                 // clamp to 448
        unsigned int r = a + 0x0007FFFFu + ((a >> 20) & 1u);  // RNE to 3 mant bits
        unsigned int e8 = r >> 23;
        if (e8 > 135u) { r = 0x43E00000u; e8 = 135u; }
        return s | (((e8 - 120u) << 3) | ((r >> 20) & 7u));
    } else {                                                   // subnormal: step 2^-9
        int q = (int)(xa * 512.0f + 0.5f);                     // 0..8 (8 -> 0x08 = 2^-6)
        return s | (unsigned int)q;
    }
}

// ---------------- fp8 e4m3fn decode-accumulate (hot path) ----------------
__device__ __forceinline__ void acc_fp8x4(float* a, unsigned int u) {
#if __has_builtin(__builtin_amdgcn_cvt_pk_f32_fp8)
    auto p0 = __builtin_amdgcn_cvt_pk_f32_fp8(u, false);
    auto p1 = __builtin_amdgcn_cvt_pk_f32_fp8(u, true);
    a[0] += p0[0]; a[1] += p0[1]; a[2] += p1[0]; a[3] += p1[1];
#else
    #pragma unroll
    for (int i = 0; i < 4; ++i) {
        unsigned int b = (u >> (8 * i)) & 0xffu;
        float d = __uint_as_float(((b & 0x7fu) << 20) | ((b & 0x80u) << 24));
        a[i] = fmaf(d, 0x1p120f, a[i]);
    }
#endif
}

// ---------------- deep-pipelined bf16 gather: wave fills 4 rows of sA mean-agg ----------------
__device__ __forceinline__ void gather4_bf16(
    const unsigned short* __restrict__ feat,
    const int* __restrict__ row_ptr, const int* __restrict__ esrc,
    int m0, unsigned short* __restrict__ sA)
{
    const int tid = threadIdx.x;
    const int wave = tid >> 6, lane = tid & 63;
    const int g = lane >> 4, c = lane & 15;
    const int base = m0 + wave * 4;

    int beg[4], deg[4], ids[4];
    int rp0 = row_ptr[base];
    #pragma unroll
    for (int j = 0; j < 4; ++j) {
        int rp1 = row_ptr[base + j + 1];
        beg[j] = rp0; deg[j] = rp1 - rp0; rp0 = rp1;
    }
    #pragma unroll
    for (int j = 0; j < 4; ++j) {
        int idx = beg[j] + c;
        idx = (idx < N_EDGES) ? idx : (N_EDGES - 1);
        ids[j] = esrc[idx];
    }

    float acc[4][8];
    #pragma unroll
    for (int j = 0; j < 4; ++j)
        #pragma unroll
        for (int k = 0; k < 8; ++k) acc[j][k] = 0.0f;

    #pragma unroll
    for (int jp = 0; jp < 2; ++jp) {
        uint4 v[2][4];
        #pragma unroll
        for (int jj = 0; jj < 2; ++jj) {
            const int j = jp * 2 + jj;
            #pragma unroll
            for (int b = 0; b < 4; ++b) {
                int s = __shfl(ids[j], b * 4 + g);
                v[jj][b] = *reinterpret_cast<const uint4*>(feat + (size_t)s * HID + c * 8);
            }
        }
        #pragma unroll
        for (int jj = 0; jj < 2; ++jj) {
            const int j = jp * 2 + jj;
            #pragma unroll
            for (int b = 0; b < 4; ++b) {
                uint4 vv = v[jj][b];
                if (b * 4 + g >= deg[j]) vv = make_uint4(0u, 0u, 0u, 0u);
                acc_u4(acc[j], vv);
            }
        }
        #pragma unroll
        for (int jj = 0; jj < 2; ++jj) {
            const int j = jp * 2 + jj;
            const int last = beg[j] + deg[j] - 1;
            for (int e0 = 16; e0 < deg[j]; e0 += 16) {
                int idx = beg[j] + e0 + c;
                int id2 = esrc[(idx < last) ? idx : last];
                uint4 w[4];
                #pragma unroll
                for (int b = 0; b < 4; ++b) {
                    int s = __shfl(id2, b * 4 + g);
                    w[b] = *reinterpret_cast<const uint4*>(feat + (size_t)s * HID + c * 8);
                }
                #pragma unroll
                for (int b = 0; b < 4; ++b) {
                    uint4 vv = w[b];
                    if (e0 + b * 4 + g >= deg[j]) vv = make_uint4(0u, 0u, 0u, 0u);
                    acc_u4(acc[j], vv);
                }
            }
        }
    }

    #pragma unroll
    for (int j = 0; j < 4; ++j) {
        const float scale = 1.0f / fmaxf((float)deg[j], 1.0f);
        float r[8];
        #pragma unroll
        for (int k = 0; k < 8; ++k) {
            float t = acc[j][k];
            t += __shfl_xor(t, 16);
            t += __shfl_xor(t, 32);
            r[k] = t * scale;
        }
        if (g == 0) {
            uint4 pk;
            pk.x = (unsigned)f2bf(r[0]) | ((unsigned)f2bf(r[1]) << 16);
            pk.y = (unsigned)f2bf(r[2]) | ((unsigned)f2bf(r[3]) << 16);
            pk.z = (unsigned)f2bf(r[4]) | ((unsigned)f2bf(r[5]) << 16);
            pk.w = (unsigned)f2bf(r[6]) | ((unsigned)f2bf(r[7]) << 16);
            *reinterpret_cast<uint4*>(&sA[(wave * 4 + j) * LDA + c * 8]) = pk;
        }
    }
}

// ---------------- fp8 gather: identical structure, 8 B/lane, 1 line/row ----------------
__device__ __forceinline__ void gather4_fp8(
    const unsigned char* __restrict__ feat8,
    const int* __restrict__ row_ptr, const int* __restrict__ esrc,
    int m0, unsigned short* __restrict__ sA)
{
    const int tid = threadIdx.x;
    const int wave = tid >> 6, lane = tid & 63;
    const int g = lane >> 4, c = lane & 15;
    const int base = m0 + wave * 4;

    int beg[4], deg[4], ids[4];
    int rp0 = row_ptr[base];
    #pragma unroll
    for (int j = 0; j < 4; ++j) {
        int rp1 = row_ptr[base + j + 1];
        beg[j] = rp0; deg[j] = rp1 - rp0; rp0 = rp1;
    }
    #pragma unroll
    for (int j = 0; j < 4; ++j) {
        int idx = beg[j] + c;
        idx = (idx < N_EDGES) ? idx : (N_EDGES - 1);
        ids[j] = esrc[idx];
    }

    float acc[4][8];
    #pragma unroll
    for (int j = 0; j < 4; ++j)
        #pragma unroll
        for (int k = 0; k < 8; ++k) acc[j][k] = 0.0f;

    #pragma unroll
    for (int jp = 0; jp < 2; ++jp) {
        uint2 v[2][4];
        #pragma unroll
        for (int jj = 0; jj < 2; ++jj) {
            const int j = jp * 2 + jj;
            #pragma unroll
            for (int b = 0; b < 4; ++b) {
                int s = __shfl(ids[j], b * 4 + g);
                v[jj][b] = *reinterpret_cast<const uint2*>(feat8 + (size_t)s * HID + c * 8);
            }
        }
        #pragma unroll
        for (int jj = 0; jj < 2; ++jj) {
            const int j = jp * 2 + jj;
            #pragma unroll
            for (int b = 0; b < 4; ++b) {
                uint2 vv = v[jj][b];
                if (b * 4 + g >= deg[j]) vv = make_uint2(0u, 0u);
                acc_fp8x4(&acc[j][0], vv.x);
                acc_fp8x4(&acc[j][4], vv.y);
            }
        }
        #pragma unroll
        for (int jj = 0; jj < 2; ++jj) {
            const int j = jp * 2 + jj;
            const int last = beg[j] + deg[j] - 1;
            for (int e0 = 16; e0 < deg[j]; e0 += 16) {
                int idx = beg[j] + e0 + c;
                int id2 = esrc[(idx < last) ? idx : last];
                uint2 w[4];
                #pragma unroll
                for (int b = 0; b < 4; ++b) {
                    int s = __shfl(id2, b * 4 + g);
                    w[b] = *reinterpret_cast<const uint2*>(feat8 + (size_t)s * HID + c * 8);
                }
                #pragma unroll
                for (int b = 0; b < 4; ++b) {
                    uint2 vv = w[b];
                    if (e0 + b * 4 + g >= deg[j]) vv = make_uint2(0u, 0u);
                    acc_fp8x4(&acc[j][0], vv.x);
                    acc_fp8x4(&acc[j][4], vv.y);
                }
            }
        }
    }

    #pragma unroll
    for (int j = 0; j < 4; ++j) {
        const float scale = 1.0f / fmaxf((float)deg[j], 1.0f);
        float r[8];
        #pragma unroll
        for (int k = 0; k < 8; ++k) {
            float t = acc[j][k];
            t += __shfl_xor(t, 16);
            t += __shfl_xor(t, 32);
            r[k] = t * scale;
        }
        if (g == 0) {
            uint4 pk;
            pk.x = (unsigned)f2bf(r[0]) | ((unsigned)f2bf(r[1]) << 16);
            pk.y = (unsigned)f2bf(r[2]) | ((unsigned)f2bf(r[3]) << 16);
            pk.z = (unsigned)f2bf(r[4]) | ((unsigned)f2bf(r[5]) << 16);
            pk.w = (unsigned)f2bf(r[6]) | ((unsigned)f2bf(r[7]) << 16);
            *reinterpret_cast<uint4*>(&sA[(wave * 4 + j) * LDA + c * 8]) = pk;
        }
    }
}

// ---------------- convert x -> bf16 [N][128] + fp8 [N][128]; weights -> bf16 [128][256] ----------------
__global__ __launch_bounds__(256) void convert_kernel(
    const float* __restrict__ x, unsigned short* __restrict__ xb,
    unsigned char* __restrict__ x8,
    const float* __restrict__ Wl1, const float* __restrict__ Wr1,
    const float* __restrict__ Wl2, const float* __restrict__ Wr2,
    unsigned short* __restrict__ wcat1, unsigned short* __restrict__ wcat2)
{
    const int b = blockIdx.x;
    if (b < N_NODES * 32 / 256) {
        int gid = b * 256 + threadIdx.x;          // over N*32
        int node = gid >> 5, c4 = gid & 31;
        float4 v = reinterpret_cast<const float4*>(x + (size_t)node * HID)[c4];
        unsigned short* o = xb + (size_t)node * HID + c4 * 4;
        o[0] = f2bf(v.x); o[1] = f2bf(v.y); o[2] = f2bf(v.z); o[3] = f2bf(v.w);
        unsigned int pk8 = f2fp8(v.x) | (f2fp8(v.y) << 8) | (f2fp8(v.z) << 16) | (f2fp8(v.w) << 24);
        *reinterpret_cast<unsigned int*>(x8 + (size_t)node * HID + c4 * 4) = pk8;
    } else {
        int idx2 = (b - N_NODES * 32 / 256) * 256 + threadIdx.x;  // over 2*128*256
        int layer = idx2 >> 15;
        int idx = idx2 & 32767;
        int n = idx >> 8, k = idx & 255;
        const float* Wl = layer ? Wl2 : Wl1;
        const float* Wr = layer ? Wr2 : Wr1;
        float v = (k < 128) ? Wl[(size_t)n * HID + k] : Wr[(size_t)n * HID + (k - 128)];
        (layer ? wcat2 : wcat1)[idx] = f2bf(v);
    }
}

// ---------------- degree histogram ----------------
__global__ void hist_kernel(const int* __restrict__ dst, int* __restrict__ cnt) {
    int e = blockIdx.x * blockDim.x + threadIdx.x;
    if (e < N_EDGES) atomicAdd(&cnt[dst[e]], 1);
}

// ---------------- 3-phase exclusive scan of cnt ----------------
__global__ __launch_bounds__(256) void scanA_kernel(const int* __restrict__ cnt,
                                                    int* __restrict__ partial) {
    const int tid = threadIdx.x;
    const int i = blockIdx.x * 256 + tid;
    int v = (i < N_NODES) ? cnt[i] : 0;
    const int lane = tid & 63, wave = tid >> 6;
    int incl = v;
    #pragma unroll
    for (int off = 1; off < 64; off <<= 1) {
        int t = __shfl_up(incl, off);
        if (lane >= off) incl += t;
    }
    __shared__ int wsum[4];
    if (lane == 63) wsum[wave] = incl;
    __syncthreads();
    if (tid == 0) partial[blockIdx.x] = wsum[0] + wsum[1] + wsum[2] + wsum[3];
}

__global__ __launch_bounds__(256) void scanB_kernel(int* __restrict__ partial) {
    const int tid = threadIdx.x;
    int v = (tid < SCAN_BLOCKS) ? partial[tid] : 0;
    const int lane = tid & 63, wave = tid >> 6;
    int incl = v;
    #pragma unroll
    for (int off = 1; off < 64; off <<= 1) {
        int t = __shfl_up(incl, off);
        if (lane >= off) incl += t;
    }
    __shared__ int wsum[4];
    if (lane == 63) wsum[wave] = incl;
    __syncthreads();
    int base = 0;
    if (wave > 0) base += wsum[0];
    if (wave > 1) base += wsum[1];
    if (wave > 2) base += wsum[2];
    if (tid < SCAN_BLOCKS) partial[tid] = base + incl - v;   // exclusive
}

__global__ __launch_bounds__(256) void scanC_kernel(int* __restrict__ cnt,
                                                    const int* __restrict__ partial,
                                                    int* __restrict__ row_ptr) {
    const int tid = threadIdx.x;
    const int i = blockIdx.x * 256 + tid;
    int v = (i < N_NODES) ? cnt[i] : 0;
    const int lane = tid & 63, wave = tid >> 6;
    int incl = v;
    #pragma unroll
    for (int off = 1; off < 64; off <<= 1) {
        int t = __shfl_up(incl, off);
        if (lane >= off) incl += t;
    }
    __shared__ int wsum[4];
    if (lane == 63) wsum[wave] = incl;
    __syncthreads();
    int base = partial[blockIdx.x];
    if (wave > 0) base += wsum[0];
    if (wave > 1) base += wsum[1];
    if (wave > 2) base += wsum[2];
    const int pre = base + incl - v;
    if (i < N_NODES) {
        cnt[i] = pre;                  // fill cursor
        row_ptr[i + 1] = pre + v;
    }
    if (i == 0) row_ptr[0] = 0;
}

// ---------------- bucket fill (cnt used as cursors) ----------------
__global__ void fill_kernel(const int* __restrict__ src, const int* __restrict__ dst,
                            int* __restrict__ cursor, int* __restrict__ esrc) {
    int e = blockIdx.x * blockDim.x + threadIdx.x;
    if (e < N_EDGES) {
        int p = atomicAdd(&cursor[dst[e]], 1);
        esrc[p] = src[e];
    }
}

// ---------------- fused gather(fp8) + SAGE layer-1 MFMA ----------------
__global__ __launch_bounds__(256) void sage1_kernel(
    const unsigned short* __restrict__ feat,   // bf16 (self term)
    const unsigned char* __restrict__ feat8,   // fp8 (gather)
    const int* __restrict__ row_ptr, const int* __restrict__ esrc,
    const unsigned short* __restrict__ Wcat, const float* __restrict__ bias,
    unsigned short* __restrict__ Hout)
{
    __shared__ unsigned short sA[16 * LDA];
    const int tid = threadIdx.x;
    const int wave = tid >> 6, lane = tid & 63;
    const int m0 = blockIdx.x * 16;

    // self columns: sA[r][128..255]
    {
        int r = tid >> 4, cc = tid & 15;
        uint4 v = reinterpret_cast<const uint4*>(feat + (size_t)(m0 + r) * HID)[cc];
        *reinterpret_cast<uint4*>(&sA[r * LDA + 128 + cc * 8]) = v;
    }
    gather4_fp8(feat8, row_ptr, esrc, m0, sA);
    __syncthreads();

    const int l15 = lane & 15, lq = lane >> 4;
    const int n0 = wave * 32;
    bf16x8 bfrag[2][8];
    #pragma unroll
    for (int nt = 0; nt < 2; ++nt) {
        const unsigned short* wrow = Wcat + (size_t)(n0 + nt * 16 + l15) * 256;
        #pragma unroll
        for (int ks = 0; ks < 8; ++ks)
            bfrag[nt][ks] = *reinterpret_cast<const bf16x8*>(wrow + ks * 32 + lq * 8);
    }
    f32x4 acc0 = {0.f, 0.f, 0.f, 0.f}, acc1 = {0.f, 0.f, 0.f, 0.f};
    #pragma unroll
    for (int ks = 0; ks < 8; ++ks) {
        bf16x8 af = *reinterpret_cast<const bf16x8*>(&sA[l15 * LDA + ks * 32 + lq * 8]);
        acc0 = __builtin_amdgcn_mfma_f32_16x16x32_bf16(af, bfrag[0][ks], acc0, 0, 0, 0);
        acc1 = __builtin_amdgcn_mfma_f32_16x16x32_bf16(af, bfrag[1][ks], acc1, 0, 0, 0);
    }
    #pragma unroll
    for (int nt = 0; nt < 2; ++nt) {
        const f32x4 a = nt ? acc1 : acc0;
        const int col = n0 + nt * 16 + l15;
        const float bv = bias[col];
        #pragma unroll
        for (int r = 0; r < 4; ++r) {
            float v = fmaxf(a[r] + bv, 0.0f);      // relu
            Hout[(size_t)(m0 + lq * 4 + r) * HID + col] = f2bf(v);
        }
    }
}

// ---------------- fused gather(bf16) + layer-2 MFMA + head + log_softmax ----------------
__global__ __launch_bounds__(256) void final_kernel(
    const unsigned short* __restrict__ feat,    // h1 [N][128] bf16
    const int* __restrict__ row_ptr, const int* __restrict__ esrc,
    const unsigned short* __restrict__ Wcat2, const float* __restrict__ bl2,
    const float* __restrict__ Wout, const float* __restrict__ bout,
    float* __restrict__ out)
{
    __shared__ __align__(16) char smem[16 * LDA * 2 + 16 * OUT_CH * 4];  // 8448 + 4096
    unsigned short* sA = (unsigned short*)smem;            // phase 1-2
    float (*sH)[132]   = (float(*)[132])smem;              // overlay, phase 3+
    float (*sL)[OUT_CH] = (float(*)[OUT_CH])(smem + 16 * LDA * 2);
    const int tid = threadIdx.x;
    const int wave = tid >> 6, lane = tid & 63;
    const int m0 = blockIdx.x * 16;

    {
        int r = tid >> 4, cc = tid & 15;
        uint4 v = reinterpret_cast<const uint4*>(feat + (size_t)(m0 + r) * HID)[cc];
        *reinterpret_cast<uint4*>(&sA[r * LDA + 128 + cc * 8]) = v;
    }
    gather4_bf16(feat, row_ptr, esrc, m0, sA);
    __syncthreads();

    const int l15 = lane & 15, lq = lane >> 4;
    const int n0 = wave * 32;
    bf16x8 bfrag[2][8];
    #pragma unroll
    for (int nt = 0; nt < 2; ++nt) {
        const unsigned short* wrow = Wcat2 + (size_t)(n0 + nt * 16 + l15) * 256;
        #pragma unroll
        for (int ks = 0; ks < 8; ++ks)
            bfrag[nt][ks] = *reinterpret_cast<const bf16x8*>(wrow + ks * 32 + lq * 8);
    }
    f32x4 acc0 = {0.f, 0.f, 0.f, 0.f}, acc1 = {0.f, 0.f, 0.f, 0.f};
    #pragma unroll
    for (int ks = 0; ks < 8; ++ks) {
        bf16x8 af = *reinterpret_cast<const bf16x8*>(&sA[l15 * LDA + ks * 32 + lq * 8]);
        acc0 = __builtin_amdgcn_mfma_f32_16x16x32_bf16(af, bfrag[0][ks], acc0, 0, 0, 0);
        acc1 = __builtin_amdgcn_mfma_f32_16x16x32_bf16(af, bfrag[1][ks], acc1, 0, 0, 0);
    }
    __syncthreads();   // all waves done reading sA before sH overlay write

    #pragma unroll
    for (int nt = 0; nt < 2; ++nt) {
        const f32x4 a = nt ? acc1 : acc0;
        const int col = n0 + nt * 16 + l15;
        const float bv = bl2[col];
        #pragma unroll
        for (int r = 0; r < 4; ++r)
            sH[lq * 4 + r][col] = a[r] + bv;
    }
    __syncthreads();

    // head: logits = h2 @ Wout^T + bout
    {
        const int o = tid & 63;
        const int jb = (tid >> 6) * 4;
        float hacc[4] = {0, 0, 0, 0};
        for (int k4 = 0; k4 < 32; ++k4) {
            float4 w = reinterpret_cast<const float4*>(Wout + (size_t)o * HID)[k4];
            #pragma unroll
            for (int j = 0; j < 4; ++j) {
                float4 h = *reinterpret_cast<const float4*>(&sH[jb + j][k4 * 4]);
                hacc[j] += w.x * h.x + w.y * h.y + w.z * h.z + w.w * h.w;
            }
        }
        const float bv = bout[o];
        #pragma unroll
        for (int j = 0; j < 4; ++j)
            sL[jb + j][o] = hacc[j] + bv;
    }
    __syncthreads();

    // log_softmax: one wave per row
    for (int r = wave; r < 16; r += 4) {
        float v = sL[r][lane];
        float m = v;
        for (int off = 32; off; off >>= 1) m = fmaxf(m, __shfl_xor(m, off));
        float ex = expf(v - m);
        float s = ex;
        for (int off = 32; off; off >>= 1) s += __shfl_xor(s, off);
        out[(size_t)(m0 + r) * OUT_CH + lane] = v - m - logf(s);
    }
}

extern "C" void kernel_launch(void* const* d_in, const int* in_sizes, int n_in,
                              void* d_out, int out_size, void* d_ws, size_t ws_size,
                              hipStream_t stream) {
    const float* x    = (const float*)d_in[0];
    const int*   edge = (const int*)d_in[1];
    const int*   src  = edge;
    const int*   dst  = edge + N_EDGES;
    const float* Wl1  = (const float*)d_in[2];
    const float* bl1  = (const float*)d_in[3];
    const float* Wr1  = (const float*)d_in[4];
    const float* Wl2  = (const float*)d_in[5];
    const float* bl2  = (const float*)d_in[6];
    const float* Wr2  = (const float*)d_in[7];
    const float* Wout = (const float*)d_in[8];
    const float* bout = (const float*)d_in[9];
    float* out = (float*)d_out;

    char* ws = (char*)d_ws;
    const size_t featBytes  = (size_t)N_NODES * HID * 2;     // 12.8 MB
    const size_t feat8Bytes = (size_t)N_NODES * HID;         // 6.4 MB
    unsigned short* xb = (unsigned short*)ws;
    unsigned char*  x8 = (unsigned char*)(ws + featBytes);
    unsigned short* h1 = (unsigned short*)(ws + featBytes + feat8Bytes);
    char* p = ws + 2 * featBytes + feat8Bytes;
    int* cnt     = (int*)p;   p += (size_t)N_NODES * 4;
    int* row_ptr = (int*)p;   p += (size_t)(N_NODES + 1) * 4 + 252;
    int* partial = (int*)p;   p += 1024;
    int* esrc    = (int*)p;   p += (size_t)N_EDGES * 4;
    unsigned short* wcat1 = (unsigned short*)p;  p += 128 * 256 * 2;
    unsigned short* wcat2 = (unsigned short*)p;

    hipMemsetAsync(cnt, 0, (size_t)N_NODES * sizeof(int), stream);
    hist_kernel<<<N_EDGES / 256, 256, 0, stream>>>(dst, cnt);
    convert_kernel<<<N_NODES * 32 / 256 + 256, 256, 0, stream>>>(
        x, xb, x8, Wl1, Wr1, Wl2, Wr2, wcat1, wcat2);
    scanA_kernel<<<SCAN_BLOCKS, 256, 0, stream>>>(cnt, partial);
    scanB_kernel<<<1, 256, 0, stream>>>(partial);
    scanC_kernel<<<SCAN_BLOCKS, 256, 0, stream>>>(cnt, partial, row_ptr);
    fill_kernel<<<N_EDGES / 256, 256, 0, stream>>>(src, dst, cnt, esrc);

    sage1_kernel<<<N_NODES / 16, 256, 0, stream>>>(xb, x8, row_ptr, esrc, wcat1, bl1, h1);
    final_kernel<<<N_NODES / 16, 256, 0, stream>>>(h1, row_ptr, esrc, wcat2, bl2,
                                                   Wout, bout, out);
}